// Round 7
// baseline (620.619 us; speedup 1.0000x reference)
//
#include <hip/hip_runtime.h>

#define B_ 4
#define T_ 2048
#define D_ 1024
#define H_ 16
#define DK_ 64
#define M_ (B_*T_)   // 8192 rows

typedef __bf16 bf16;
typedef __bf16 bf16x8 __attribute__((ext_vector_type(8)));
typedef __bf16 bf16x4 __attribute__((ext_vector_type(4)));
typedef short s16x4 __attribute__((ext_vector_type(4)));
typedef float f32x4 __attribute__((ext_vector_type(4)));

__device__ __forceinline__ f32x4 zero4() { f32x4 v = {0.f, 0.f, 0.f, 0.f}; return v; }

// async global->LDS, 16B per lane; LDS base wave-uniform, HW adds lane*16
__device__ __forceinline__ void g2l16(const void* g, void* l) {
  __builtin_amdgcn_global_load_lds(
      (const __attribute__((address_space(1))) void*)g,
      (__attribute__((address_space(3))) void*)l, 16, 0, 0);
}

// ---------------- x fp32 -> bf16, written into qkv's V-columns (stride 3*D_) ----------------
__global__ __launch_bounds__(256) void conv_bf16(const float* __restrict__ src,
                                                 bf16* __restrict__ dst) {
  const size_t g = (size_t)blockIdx.x * 256 + threadIdx.x;  // 8 elems/thread
  const int row = g >> 7, col = (g & 127) * 8;
  const float4 a = *(const float4*)(src + (size_t)row * D_ + col);
  const float4 b = *(const float4*)(src + (size_t)row * D_ + col + 4);
  bf16x8 o;
  o[0] = (bf16)a.x; o[1] = (bf16)a.y; o[2] = (bf16)a.z; o[3] = (bf16)a.w;
  o[4] = (bf16)b.x; o[5] = (bf16)b.y; o[6] = (bf16)b.z; o[7] = (bf16)b.w;
  *(bf16x8*)(dst + (size_t)row * (3 * D_) + col) = o;
}

// ---------------- weight transpose + cast: dst[C][R] = (bf16)src[R][C] ----------------
__global__ __launch_bounds__(256) void transpose_wf(const float* __restrict__ src,
                                                    bf16* __restrict__ dst, int R, int C) {
  __shared__ alignas(16) bf16 ts[64 * 65];
  const int tid = threadIdx.x;
  const int r0 = blockIdx.x * 64, c0 = blockIdx.y * 64;
  {
    int rr = tid >> 2, cc = (tid & 3) * 16;
    const float4* p4 = (const float4*)(src + (size_t)(r0 + rr) * C + c0 + cc);
    float fv[16];
#pragma unroll
    for (int q = 0; q < 4; ++q) *(float4*)&fv[q * 4] = p4[q];
#pragma unroll
    for (int i = 0; i < 16; ++i) ts[(cc + i) * 65 + rr] = (bf16)fv[i];
  }
  __syncthreads();
  {
    int rr = tid >> 2, cc = (tid & 3) * 16;
    bf16x8 a, b;
#pragma unroll
    for (int i = 0; i < 8; ++i) a[i] = ts[rr * 65 + cc + i];
#pragma unroll
    for (int i = 0; i < 8; ++i) b[i] = ts[rr * 65 + cc + 8 + i];
    bf16* q = dst + (size_t)(c0 + rr) * R + r0 + cc;
    *(bf16x8*)q = a;
    *(bf16x8*)(q + 8) = b;
  }
}

// ---------------- GEMM: C[M][N] = A[M][K] @ Bt[N][K]^T + bias (full-DMA m97 staging) ----------------
// FUSE=true: Cf32 = C + resid(fp32), stride N.
// FUSE=false: col<2048 -> Cbf[row*ldc+col]; col>=2048 (V part) -> transposed into VtOut[b,h,f,t].
template <bool FUSE>
__global__ __launch_bounds__(256) void gemm128(const bf16* __restrict__ A,
                                               const bf16* __restrict__ Bt,
                                               const float* __restrict__ bias,
                                               bf16* __restrict__ Cbf,
                                               bf16* __restrict__ VtOut,
                                               float* __restrict__ Cf,
                                               const float* __restrict__ resid,
                                               int N, int K, int lda, int ldc) {
  __shared__ alignas(16) bf16 As[128 * 32];
  __shared__ alignas(16) bf16 Bs[128 * 32];
  const int tid = threadIdx.x;
  const int wid = tid >> 6, lane = tid & 63, quad = lane >> 4, l16 = lane & 15;
  const int m0 = blockIdx.x * 128, n0 = blockIdx.y * 128;
  const int wr = (wid >> 1) * 64, wc = (wid & 1) * 64;

  f32x4 acc[4][4];
#pragma unroll
  for (int i = 0; i < 4; ++i)
#pragma unroll
    for (int j = 0; j < 4; ++j) acc[i][j] = zero4();

  for (int k0 = 0; k0 < K; k0 += 32) {
    __syncthreads();
#pragma unroll
    for (int p = 0; p < 2; ++p) {
      int t = p * 256 + tid;
      int row = t >> 2, kc = (t & 3) * 8;
      g2l16(A + (size_t)(m0 + row) * lda + k0 + kc, (char*)As + p * 4096 + wid * 1024);
      g2l16(Bt + (size_t)(n0 + row) * K + k0 + kc, (char*)Bs + p * 4096 + wid * 1024);
    }
    __syncthreads();
    bf16x8 af[4], bfr[4];
#pragma unroll
    for (int i = 0; i < 4; ++i)
      af[i] = *(const bf16x8*)&As[(wr + i * 16 + l16) * 32 + quad * 8];
#pragma unroll
    for (int j = 0; j < 4; ++j)
      bfr[j] = *(const bf16x8*)&Bs[(wc + j * 16 + l16) * 32 + quad * 8];
#pragma unroll
    for (int i = 0; i < 4; ++i)
#pragma unroll
      for (int j = 0; j < 4; ++j)
        acc[i][j] = __builtin_amdgcn_mfma_f32_16x16x32_bf16(af[i], bfr[j], acc[i][j], 0, 0, 0);
  }

  if (!FUSE && n0 >= 2 * D_) {
    // V region: store transposed into VtOut[b][h][f][t], 4 t-values packed per store
#pragma unroll
    for (int i = 0; i < 4; ++i) {
      const int rowbase = m0 + wr + i * 16 + quad * 4;       // multiple of 4
      const int bb = rowbase >> 11, t = rowbase & (T_ - 1);  // block never straddles b
#pragma unroll
      for (int j = 0; j < 4; ++j) {
        const int col = n0 + wc + j * 16 + l16;
        const float bv = bias[col];
        const int fg = col - 2 * D_;
        bf16x4 pv;
#pragma unroll
        for (int r = 0; r < 4; ++r) pv[r] = (bf16)(acc[i][j][r] + bv);
        *(bf16x4*)(VtOut + ((size_t)(bb * H_ + (fg >> 6)) * DK_ + (fg & 63)) * T_ + t) = pv;
      }
    }
    return;
  }

#pragma unroll
  for (int i = 0; i < 4; ++i) {
#pragma unroll
    for (int j = 0; j < 4; ++j) {
      const int col = n0 + wc + j * 16 + l16;
      const float bv = bias[col];
#pragma unroll
      for (int r = 0; r < 4; ++r) {
        const int row = m0 + wr + i * 16 + quad * 4 + r;
        const float v = acc[i][j][r] + bv;
        if (FUSE) {
          const size_t off = (size_t)row * N + col;
          Cf[off] = v + resid[off];
        } else {
          Cbf[(size_t)row * ldc + col] = (bf16)v;
        }
      }
    }
  }
}

// ---------------- flash attention: block = (b, h, 128 q-rows), 8 waves x 16 rows ----------------
// S^T = K Q^T (C-layout row=key, col=qrow); P stays in registers feeding 16x16x16 PV.
// Softmax in log2 domain (Q pre-scaled by log2e/8). Shared K/V LDS across 8 waves -> 4 blocks/CU.
__global__ __launch_bounds__(512, 8) void attn128(const bf16* __restrict__ qkv,
                                                  const bf16* __restrict__ Vt,
                                                  bf16* __restrict__ out) {
  __shared__ alignas(16) bf16 Ks[128 * 72];      // [key][f], stride 72
  __shared__ alignas(16) bf16 Vs[64 * 136];      // [f][key], stride 136
  const int tid = threadIdx.x;
  const int wid = tid >> 6, lane = tid & 63, quad = lane >> 4, l16 = lane & 15;
  const int bid = blockIdx.x;
  const int qb = bid & 15, h = (bid >> 4) & 15, b = bid >> 8;
  const int q0 = qb * 128;

  // Q as MFMA B-operand (k=quad*8+j, n=qrow=l16), pre-scaled by log2e/8
  const float SC = 0.125f * 1.44269504f;
  bf16x8 qf[2];
  {
    const bf16* qp = qkv + (size_t)(b * T_ + q0 + wid * 16 + l16) * (3 * D_) + h * DK_ + quad * 8;
    qf[0] = *(const bf16x8*)qp;
    qf[1] = *(const bf16x8*)(qp + 32);
#pragma unroll
    for (int i = 0; i < 8; ++i) { qf[0][i] = (bf16)((float)qf[0][i] * SC);
                                  qf[1][i] = (bf16)((float)qf[1][i] * SC); }
  }

  float mi = -1e30f, li = 0.f;   // per-lane: qrow = l16 (replicated across quads)
  f32x4 o[4];                    // o[ft][r] = O[qrow=quad*4+r][f=ft*16+l16]
#pragma unroll
  for (int ft = 0; ft < 4; ++ft) o[ft] = zero4();

  for (int kt = 0; kt < T_ / 128; ++kt) {
    __syncthreads();
#pragma unroll
    for (int p = 0; p < 2; ++p) {
      int c = p * 512 + tid;            // [0,1024)
      int key = c >> 3, f = (c & 7) * 8;
      *(bf16x8*)&Ks[key * 72 + f] =
          *(const bf16x8*)(qkv + (size_t)(b * T_ + kt * 128 + key) * (3 * D_) + D_ + h * DK_ + f);
      int vf = c >> 4, kc = (c & 15) * 8;
      *(bf16x8*)&Vs[vf * 136 + kc] =
          *(const bf16x8*)(Vt + ((size_t)(b * H_ + h) * DK_ + vf) * T_ + kt * 128 + kc);
    }
    __syncthreads();

    // S^T tile (log2 domain): sv[nt] reg r = S2[key = nt*16+quad*4+r][qrow = l16]
    f32x4 sv[8];
#pragma unroll
    for (int nt = 0; nt < 8; ++nt) sv[nt] = zero4();
#pragma unroll
    for (int nt = 0; nt < 8; ++nt)
#pragma unroll
      for (int ks = 0; ks < 2; ++ks) {
        bf16x8 kf = *(const bf16x8*)&Ks[(nt * 16 + l16) * 72 + ks * 32 + quad * 8];
        sv[nt] = __builtin_amdgcn_mfma_f32_16x16x32_bf16(kf, qf[ks], sv[nt], 0, 0, 0);
      }

    // online softmax (base-2): lane owns 32 scores of qrow=l16
    float tmax = mi;
#pragma unroll
    for (int nt = 0; nt < 8; ++nt)
#pragma unroll
      for (int r = 0; r < 4; ++r) tmax = fmaxf(tmax, sv[nt][r]);
    tmax = fmaxf(tmax, __shfl_xor(tmax, 16, 64));
    tmax = fmaxf(tmax, __shfl_xor(tmax, 32, 64));
    const float alpha = exp2f(mi - tmax);
    mi = tmax;
    float s = 0.f;
#pragma unroll
    for (int nt = 0; nt < 8; ++nt)
#pragma unroll
      for (int r = 0; r < 4; ++r) {
        float pe = exp2f(sv[nt][r] - tmax);
        sv[nt][r] = pe; s += pe;
      }
    s += __shfl_xor(s, 16, 64);
    s += __shfl_xor(s, 32, 64);
    li = li * alpha + s;

    // rescale O: row quad*4+r's alpha lives at lane quad*4+r
#pragma unroll
    for (int r = 0; r < 4; ++r) {
      const float ar = __shfl(alpha, quad * 4 + r, 64);
#pragma unroll
      for (int ft = 0; ft < 4; ++ft) o[ft][r] *= ar;
    }

    // O += P V via 16x16x16 (A=P in registers: k=key=ks*16+quad*4+j)
#pragma unroll
    for (int ks = 0; ks < 8; ++ks) {
      union { bf16x4 b; s16x4 s; } pf;
#pragma unroll
      for (int j = 0; j < 4; ++j) pf.b[j] = (bf16)sv[ks][j];
#pragma unroll
      for (int ft = 0; ft < 4; ++ft) {
        const s16x4 vf = *(const s16x4*)&Vs[(ft * 16 + l16) * 136 + ks * 16 + quad * 4];
        o[ft] = __builtin_amdgcn_mfma_f32_16x16x16bf16_1k(pf.s, vf, o[ft], 0, 0, 0);
      }
    }
  }

  // epilogue: normalize rows (li for qrow=quad*4+r lives at lane quad*4+r)
#pragma unroll
  for (int r = 0; r < 4; ++r) {
    const float inv = 1.0f / __shfl(li, quad * 4 + r, 64);
    const int row = b * T_ + q0 + wid * 16 + quad * 4 + r;
#pragma unroll
    for (int ft = 0; ft < 4; ++ft)
      out[(size_t)row * (3 * D_) + h * DK_ + ft * 16 + l16] = (bf16)(o[ft][r] * inv);
  }
}

// ---------------- layernorm: one wave per row, in-place, no LDS/barrier ----------------
__global__ __launch_bounds__(256) void ln_out(float* __restrict__ res,
                                              const float* __restrict__ gamma,
                                              const float* __restrict__ beta) {
  const int row = blockIdx.x * 4 + (threadIdx.x >> 6);
  const int lane = threadIdx.x & 63;
  float4 v[4];
  float s = 0.f, q = 0.f;
#pragma unroll
  for (int p = 0; p < 4; ++p) {
    v[p] = *(const float4*)(res + (size_t)row * D_ + p * 256 + lane * 4);
    s += v[p].x + v[p].y + v[p].z + v[p].w;
    q += v[p].x * v[p].x + v[p].y * v[p].y + v[p].z * v[p].z + v[p].w * v[p].w;
  }
#pragma unroll
  for (int m = 1; m < 64; m <<= 1) { s += __shfl_xor(s, m, 64); q += __shfl_xor(q, m, 64); }
  const float mu = s * (1.0f / D_);
  const float var = q * (1.0f / D_) - mu * mu;
  const float rstd = rsqrtf(var + 1e-5f);
#pragma unroll
  for (int p = 0; p < 4; ++p) {
    const int c = p * 256 + lane * 4;
    const float4 g = *(const float4*)(gamma + c);
    const float4 be = *(const float4*)(beta + c);
    float4 ov;
    ov.x = (v[p].x - mu) * rstd * g.x + be.x;
    ov.y = (v[p].y - mu) * rstd * g.y + be.y;
    ov.z = (v[p].z - mu) * rstd * g.z + be.z;
    ov.w = (v[p].w - mu) * rstd * g.w + be.w;
    *(float4*)(res + (size_t)row * D_ + c) = ov;
  }
}

extern "C" void kernel_launch(void* const* d_in, const int* in_sizes, int n_in,
                              void* d_out, int out_size, void* d_ws, size_t ws_size,
                              hipStream_t stream) {
  const float* x     = (const float*)d_in[0];
  const float* Wqkv  = (const float*)d_in[1];
  const float* bqkv  = (const float*)d_in[2];
  const float* Wout  = (const float*)d_in[3];
  const float* bout  = (const float*)d_in[4];
  const float* gamma = (const float*)d_in[5];
  const float* beta  = (const float*)d_in[6];
  float* out = (float*)d_out;  // fp32 residual buffer too (LN in-place)

  // workspace layout (75.5 MB, proven footprint):
  char* ws = (char*)d_ws;
  bf16* WqkvT = (bf16*)ws; ws += (size_t)3 * D_ * D_ * 2;        // [3072][1024]
  bf16* WoutT = (bf16*)ws; ws += (size_t)D_ * D_ * 2;            // [1024][1024]
  bf16* qkv   = (bf16*)ws; ws += (size_t)M_ * 3 * D_ * 2;        // [8192][3072] (V cols multi-use)
  bf16* Vt    = (bf16*)ws;                                       // [4][16][64][2048]
  bf16* xb    = qkv + 2 * D_;  // bf16 x in qkv's V columns (stride 3*D_), dead after qkv GEMM
  bf16* attn  = qkv + 2 * D_;  // attn output re-uses the same columns afterwards

  conv_bf16<<<M_ * D_ / (256 * 8), 256, 0, stream>>>(x, xb);
  transpose_wf<<<dim3(D_ / 64, 3 * D_ / 64), 256, 0, stream>>>(Wqkv, WqkvT, D_, 3 * D_);
  transpose_wf<<<dim3(D_ / 64, D_ / 64), 256, 0, stream>>>(Wout, WoutT, D_, D_);
  gemm128<false><<<dim3(M_ / 128, 3 * D_ / 128), 256, 0, stream>>>(
      xb, WqkvT, bqkv, qkv, Vt, nullptr, nullptr, 3 * D_, D_, 3 * D_, 3 * D_);
  attn128<<<B_ * H_ * (T_ / 128), 512, 0, stream>>>(qkv, Vt, attn);
  gemm128<true><<<dim3(M_ / 128, D_ / 128), 256, 0, stream>>>(
      attn, WoutT, bout, nullptr, nullptr, out, x, D_, D_, 3 * D_, D_);
  ln_out<<<M_ / 4, 256, 0, stream>>>(out, gamma, beta);
}

// Round 8
// 379.462 us; speedup vs baseline: 1.6355x; 1.6355x over previous
//
#include <hip/hip_runtime.h>

#define B_ 4
#define T_ 2048
#define D_ 1024
#define H_ 16
#define DK_ 64
#define M_ (B_*T_)   // 8192 rows

typedef __bf16 bf16;
typedef __bf16 bf16x8 __attribute__((ext_vector_type(8)));
typedef __bf16 bf16x4 __attribute__((ext_vector_type(4)));
typedef short s16x4 __attribute__((ext_vector_type(4)));
typedef float f32x4 __attribute__((ext_vector_type(4)));

__device__ __forceinline__ f32x4 zero4() { f32x4 v = {0.f, 0.f, 0.f, 0.f}; return v; }

// async global->LDS, 16B per lane; LDS base wave-uniform, HW adds lane*16
__device__ __forceinline__ void g2l16(const void* g, void* l) {
  __builtin_amdgcn_global_load_lds(
      (const __attribute__((address_space(1))) void*)g,
      (__attribute__((address_space(3))) void*)l, 16, 0, 0);
}

// ---------------- weight transpose + cast: dst[C][R] = (bf16)src[R][C] ----------------
__global__ __launch_bounds__(256) void transpose_wf(const float* __restrict__ src,
                                                    bf16* __restrict__ dst, int R, int C) {
  __shared__ alignas(16) bf16 ts[64 * 65];
  const int tid = threadIdx.x;
  const int r0 = blockIdx.x * 64, c0 = blockIdx.y * 64;
  {
    int rr = tid >> 2, cc = (tid & 3) * 16;
    const float4* p4 = (const float4*)(src + (size_t)(r0 + rr) * C + c0 + cc);
    float fv[16];
#pragma unroll
    for (int q = 0; q < 4; ++q) *(float4*)&fv[q * 4] = p4[q];
#pragma unroll
    for (int i = 0; i < 16; ++i) ts[(cc + i) * 65 + rr] = (bf16)fv[i];
  }
  __syncthreads();
  {
    int rr = tid >> 2, cc = (tid & 3) * 16;
    bf16x8 a, b;
#pragma unroll
    for (int i = 0; i < 8; ++i) a[i] = ts[rr * 65 + cc + i];
#pragma unroll
    for (int i = 0; i < 8; ++i) b[i] = ts[rr * 65 + cc + 8 + i];
    bf16* q = dst + (size_t)(c0 + rr) * R + r0 + cc;
    *(bf16x8*)q = a;
    *(bf16x8*)(q + 8) = b;
  }
}

// ---------------- V transpose: Vt[b][h][f][t] = qkv[b*T+t][2D + h*64 + f] ----------------
__global__ __launch_bounds__(256) void transpose_v(const bf16* __restrict__ qkv,
                                                   bf16* __restrict__ Vt) {
  __shared__ alignas(16) bf16 ts[64 * 65];
  int bid = blockIdx.x;
  const int tt = bid & 31; bid >>= 5;
  const int h = bid & 15;  const int b = bid >> 4;
  const int t0 = tt * 64;
  const int tid = threadIdx.x;
  {
    int tok = tid >> 2, fc = (tid & 3) * 16;
    const bf16* p = qkv + (size_t)(b * T_ + t0 + tok) * (3 * D_) + 2 * D_ + h * DK_ + fc;
    bf16x8 a = *(const bf16x8*)p;
    bf16x8 c = *(const bf16x8*)(p + 8);
#pragma unroll
    for (int i = 0; i < 8; ++i) ts[(fc + i) * 65 + tok] = a[i];
#pragma unroll
    for (int i = 0; i < 8; ++i) ts[(fc + 8 + i) * 65 + tok] = c[i];
  }
  __syncthreads();
  {
    int f = tid >> 2, tc = (tid & 3) * 16;
    bf16x8 a, c;
#pragma unroll
    for (int i = 0; i < 8; ++i) a[i] = ts[f * 65 + tc + i];
#pragma unroll
    for (int i = 0; i < 8; ++i) c[i] = ts[f * 65 + tc + 8 + i];
    bf16* q = Vt + ((size_t)(b * H_ + h) * DK_ + f) * T_ + t0 + tc;
    *(bf16x8*)q = a;
    *(bf16x8*)(q + 8) = c;
  }
}

// ---------------- GEMM: C[M][N] = A[M][K] @ Bt[N][K]^T + bias ----------------
// ASRC=0: A fp32, cast during register staging. ASRC=1: A bf16, DMA-staged.
// B always DMA-staged (m97 pattern). FUSE: Cf32 = C + resid(fp32), stride N.
template <int ASRC, bool FUSE>
__global__ __launch_bounds__(256) void gemm128(const void* __restrict__ Av,
                                               const bf16* __restrict__ Bt,
                                               const float* __restrict__ bias,
                                               bf16* __restrict__ Cbf,
                                               float* __restrict__ Cf,
                                               const float* __restrict__ resid,
                                               int N, int K, int lda, int ldc) {
  __shared__ alignas(16) bf16 As[128 * 32];
  __shared__ alignas(16) bf16 Bs[128 * 32];
  const int tid = threadIdx.x;
  const int wid = tid >> 6, lane = tid & 63, quad = lane >> 4, l16 = lane & 15;
  const int m0 = blockIdx.x * 128, n0 = blockIdx.y * 128;
  const int wr = (wid >> 1) * 64, wc = (wid & 1) * 64;

  f32x4 acc[4][4];
#pragma unroll
  for (int i = 0; i < 4; ++i)
#pragma unroll
    for (int j = 0; j < 4; ++j) acc[i][j] = zero4();

  for (int k0 = 0; k0 < K; k0 += 32) {
    bf16x8 ar[2];
    if (ASRC == 0) {
#pragma unroll
      for (int p = 0; p < 2; ++p) {
        int t = p * 256 + tid;
        int row = t >> 2, kc = (t & 3) * 8;
        const float* ap = (const float*)Av + (size_t)(m0 + row) * lda + k0 + kc;
        float4 a0 = *(const float4*)ap, a1 = *(const float4*)(ap + 4);
        bf16x8 v;
        v[0] = (bf16)a0.x; v[1] = (bf16)a0.y; v[2] = (bf16)a0.z; v[3] = (bf16)a0.w;
        v[4] = (bf16)a1.x; v[5] = (bf16)a1.y; v[6] = (bf16)a1.z; v[7] = (bf16)a1.w;
        ar[p] = v;
      }
    }
    __syncthreads();  // previous iteration's LDS reads complete
#pragma unroll
    for (int p = 0; p < 2; ++p) {
      int t = p * 256 + tid;
      int row = t >> 2, kc = (t & 3) * 8;
      g2l16(Bt + (size_t)(n0 + row) * K + k0 + kc, (char*)Bs + p * 4096 + wid * 1024);
      if (ASRC == 1)
        g2l16((const bf16*)Av + (size_t)(m0 + row) * lda + k0 + kc,
              (char*)As + p * 4096 + wid * 1024);
      else
        *(bf16x8*)&As[row * 32 + kc] = ar[p];
    }
    __syncthreads();
    bf16x8 af[4], bfr[4];
#pragma unroll
    for (int i = 0; i < 4; ++i)
      af[i] = *(const bf16x8*)&As[(wr + i * 16 + l16) * 32 + quad * 8];
#pragma unroll
    for (int j = 0; j < 4; ++j)
      bfr[j] = *(const bf16x8*)&Bs[(wc + j * 16 + l16) * 32 + quad * 8];
#pragma unroll
    for (int i = 0; i < 4; ++i)
#pragma unroll
      for (int j = 0; j < 4; ++j)
        acc[i][j] = __builtin_amdgcn_mfma_f32_16x16x32_bf16(af[i], bfr[j], acc[i][j], 0, 0, 0);
  }

#pragma unroll
  for (int i = 0; i < 4; ++i) {
#pragma unroll
    for (int j = 0; j < 4; ++j) {
      const int col = n0 + wc + j * 16 + l16;
      const float bv = bias[col];
#pragma unroll
      for (int r = 0; r < 4; ++r) {
        const int row = m0 + wr + i * 16 + quad * 4 + r;
        const float v = acc[i][j][r] + bv;
        if (FUSE) {
          const size_t off = (size_t)row * N + col;
          Cf[off] = v + resid[off];
        } else {
          Cbf[(size_t)row * ldc + col] = (bf16)v;
        }
      }
    }
  }
}

// ---------------- flash attention: block = (b, h, 128 q-rows), 8 waves x 16 rows ----------------
// S^T = K Q^T (C-layout row=key, col=qrow); P stays in registers feeding 16x16x16 PV.
// Softmax in log2 domain. 8 waves share one K/V LDS tile; NO min-waves clause (round-7
// lesson: __launch_bounds__(512,8) capped unified VGPR+AGPR at 64 -> massive scratch spill).
__global__ __launch_bounds__(512) void attn128(const bf16* __restrict__ qkv,
                                               const bf16* __restrict__ Vt,
                                               bf16* __restrict__ out) {
  __shared__ alignas(16) bf16 Ks[128 * 72];      // [key][f], stride 72
  __shared__ alignas(16) bf16 Vs[64 * 136];      // [f][key], stride 136
  const int tid = threadIdx.x;
  const int wid = tid >> 6, lane = tid & 63, quad = lane >> 4, l16 = lane & 15;
  const int bid = blockIdx.x;
  const int qb = bid & 15, h = (bid >> 4) & 15, b = bid >> 8;
  const int q0 = qb * 128;

  // Q as MFMA B-operand (k=quad*8+j, n=qrow=l16), pre-scaled by log2e/8
  const float SC = 0.125f * 1.44269504f;
  bf16x8 qf[2];
  {
    const bf16* qp = qkv + (size_t)(b * T_ + q0 + wid * 16 + l16) * (3 * D_) + h * DK_ + quad * 8;
    qf[0] = *(const bf16x8*)qp;
    qf[1] = *(const bf16x8*)(qp + 32);
#pragma unroll
    for (int i = 0; i < 8; ++i) { qf[0][i] = (bf16)((float)qf[0][i] * SC);
                                  qf[1][i] = (bf16)((float)qf[1][i] * SC); }
  }

  float mi = -1e30f, li = 0.f;   // per-lane: qrow = l16 (replicated across quads)
  f32x4 o[4];                    // o[ft][r] = O[qrow=quad*4+r][f=ft*16+l16]
#pragma unroll
  for (int ft = 0; ft < 4; ++ft) o[ft] = zero4();

  for (int kt = 0; kt < T_ / 128; ++kt) {
    __syncthreads();
#pragma unroll
    for (int p = 0; p < 2; ++p) {
      int c = p * 512 + tid;            // [0,1024)
      int key = c >> 3, f = (c & 7) * 8;
      *(bf16x8*)&Ks[key * 72 + f] =
          *(const bf16x8*)(qkv + (size_t)(b * T_ + kt * 128 + key) * (3 * D_) + D_ + h * DK_ + f);
      int vf = c >> 4, kc = (c & 15) * 8;
      *(bf16x8*)&Vs[vf * 136 + kc] =
          *(const bf16x8*)(Vt + ((size_t)(b * H_ + h) * DK_ + vf) * T_ + kt * 128 + kc);
    }
    __syncthreads();

    // S^T tile (log2 domain): sv[nt] reg r = S2[key = nt*16+quad*4+r][qrow = l16]
    f32x4 sv[8];
#pragma unroll
    for (int nt = 0; nt < 8; ++nt) sv[nt] = zero4();
#pragma unroll
    for (int nt = 0; nt < 8; ++nt)
#pragma unroll
      for (int ks = 0; ks < 2; ++ks) {
        bf16x8 kf = *(const bf16x8*)&Ks[(nt * 16 + l16) * 72 + ks * 32 + quad * 8];
        sv[nt] = __builtin_amdgcn_mfma_f32_16x16x32_bf16(kf, qf[ks], sv[nt], 0, 0, 0);
      }

    // online softmax (base-2): lane owns 32 scores of qrow=l16
    float tmax = mi;
#pragma unroll
    for (int nt = 0; nt < 8; ++nt)
#pragma unroll
      for (int r = 0; r < 4; ++r) tmax = fmaxf(tmax, sv[nt][r]);
    tmax = fmaxf(tmax, __shfl_xor(tmax, 16, 64));
    tmax = fmaxf(tmax, __shfl_xor(tmax, 32, 64));
    const float alpha = exp2f(mi - tmax);
    mi = tmax;
    float s = 0.f;
#pragma unroll
    for (int nt = 0; nt < 8; ++nt)
#pragma unroll
      for (int r = 0; r < 4; ++r) {
        float pe = exp2f(sv[nt][r] - tmax);
        sv[nt][r] = pe; s += pe;
      }
    s += __shfl_xor(s, 16, 64);
    s += __shfl_xor(s, 32, 64);
    li = li * alpha + s;

    // rescale O: row quad*4+r's alpha lives at lane quad*4+r
#pragma unroll
    for (int r = 0; r < 4; ++r) {
      const float ar = __shfl(alpha, quad * 4 + r, 64);
#pragma unroll
      for (int ft = 0; ft < 4; ++ft) o[ft][r] *= ar;
    }

    // O += P V via 16x16x16 (A=P in registers: k=key=ks*16+quad*4+j)
#pragma unroll
    for (int ks = 0; ks < 8; ++ks) {
      union { bf16x4 b; s16x4 s; } pf;
#pragma unroll
      for (int j = 0; j < 4; ++j) pf.b[j] = (bf16)sv[ks][j];
#pragma unroll
      for (int ft = 0; ft < 4; ++ft) {
        const s16x4 vf = *(const s16x4*)&Vs[(ft * 16 + l16) * 136 + ks * 16 + quad * 4];
        o[ft] = __builtin_amdgcn_mfma_f32_16x16x16bf16_1k(pf.s, vf, o[ft], 0, 0, 0);
      }
    }
  }

  // epilogue: normalize rows (li for qrow=quad*4+r lives at lane quad*4+r)
#pragma unroll
  for (int r = 0; r < 4; ++r) {
    const float inv = 1.0f / __shfl(li, quad * 4 + r, 64);
    const int row = b * T_ + q0 + wid * 16 + quad * 4 + r;
#pragma unroll
    for (int ft = 0; ft < 4; ++ft)
      out[(size_t)row * (3 * D_) + h * DK_ + ft * 16 + l16] = (bf16)(o[ft][r] * inv);
  }
}

// ---------------- layernorm: one wave per row, in-place, no LDS/barrier ----------------
__global__ __launch_bounds__(256) void ln_out(float* __restrict__ res,
                                              const float* __restrict__ gamma,
                                              const float* __restrict__ beta) {
  const int row = blockIdx.x * 4 + (threadIdx.x >> 6);
  const int lane = threadIdx.x & 63;
  float4 v[4];
  float s = 0.f, q = 0.f;
#pragma unroll
  for (int p = 0; p < 4; ++p) {
    v[p] = *(const float4*)(res + (size_t)row * D_ + p * 256 + lane * 4);
    s += v[p].x + v[p].y + v[p].z + v[p].w;
    q += v[p].x * v[p].x + v[p].y * v[p].y + v[p].z * v[p].z + v[p].w * v[p].w;
  }
#pragma unroll
  for (int m = 1; m < 64; m <<= 1) { s += __shfl_xor(s, m, 64); q += __shfl_xor(q, m, 64); }
  const float mu = s * (1.0f / D_);
  const float var = q * (1.0f / D_) - mu * mu;
  const float rstd = rsqrtf(var + 1e-5f);
#pragma unroll
  for (int p = 0; p < 4; ++p) {
    const int c = p * 256 + lane * 4;
    const float4 g = *(const float4*)(gamma + c);
    const float4 be = *(const float4*)(beta + c);
    float4 ov;
    ov.x = (v[p].x - mu) * rstd * g.x + be.x;
    ov.y = (v[p].y - mu) * rstd * g.y + be.y;
    ov.z = (v[p].z - mu) * rstd * g.z + be.z;
    ov.w = (v[p].w - mu) * rstd * g.w + be.w;
    *(float4*)(res + (size_t)row * D_ + c) = ov;
  }
}

extern "C" void kernel_launch(void* const* d_in, const int* in_sizes, int n_in,
                              void* d_out, int out_size, void* d_ws, size_t ws_size,
                              hipStream_t stream) {
  const float* x     = (const float*)d_in[0];
  const float* Wqkv  = (const float*)d_in[1];
  const float* bqkv  = (const float*)d_in[2];
  const float* Wout  = (const float*)d_in[3];
  const float* bout  = (const float*)d_in[4];
  const float* gamma = (const float*)d_in[5];
  const float* beta  = (const float*)d_in[6];
  float* out = (float*)d_out;  // fp32 residual buffer too (LN in-place)

  // workspace layout (75.5 MB, proven footprint):
  char* ws = (char*)d_ws;
  bf16* WqkvT = (bf16*)ws; ws += (size_t)3 * D_ * D_ * 2;        // [3072][1024]
  bf16* WoutT = (bf16*)ws; ws += (size_t)D_ * D_ * 2;            // [1024][1024]
  bf16* qkv   = (bf16*)ws; ws += (size_t)M_ * 3 * D_ * 2;        // [8192][3072]
  bf16* Vt    = (bf16*)ws;                                       // [4][16][64][2048]
  bf16* attn  = qkv + 2 * D_;  // attn output overwrites qkv's V columns (dead after transpose_v)

  transpose_wf<<<dim3(D_ / 64, 3 * D_ / 64), 256, 0, stream>>>(Wqkv, WqkvT, D_, 3 * D_);
  transpose_wf<<<dim3(D_ / 64, D_ / 64), 256, 0, stream>>>(Wout, WoutT, D_, D_);
  gemm128<0, false><<<dim3(M_ / 128, 3 * D_ / 128), 256, 0, stream>>>(
      x, WqkvT, bqkv, qkv, nullptr, nullptr, 3 * D_, D_, D_, 3 * D_);
  transpose_v<<<B_ * H_ * (T_ / 64), 256, 0, stream>>>(qkv, Vt);
  attn128<<<B_ * H_ * (T_ / 128), 512, 0, stream>>>(qkv, Vt, attn);
  gemm128<1, true><<<dim3(M_ / 128, D_ / 128), 256, 0, stream>>>(
      attn, WoutT, bout, nullptr, out, x, D_, D_, 3 * D_, D_);
  ln_out<<<M_ / 4, 256, 0, stream>>>(out, gamma, beta);
}

// Round 9
// 370.828 us; speedup vs baseline: 1.6736x; 1.0233x over previous
//
#include <hip/hip_runtime.h>

#define B_ 4
#define T_ 2048
#define D_ 1024
#define H_ 16
#define DK_ 64
#define M_ (B_*T_)   // 8192 rows

typedef __bf16 bf16;
typedef __bf16 bf16x8 __attribute__((ext_vector_type(8)));
typedef __bf16 bf16x4 __attribute__((ext_vector_type(4)));
typedef short s16x4 __attribute__((ext_vector_type(4)));
typedef float f32x4 __attribute__((ext_vector_type(4)));

__device__ __forceinline__ f32x4 zero4() { f32x4 v = {0.f, 0.f, 0.f, 0.f}; return v; }

// async global->LDS, 16B per lane; LDS base wave-uniform, HW adds lane*16
__device__ __forceinline__ void g2l16(const void* g, void* l) {
  __builtin_amdgcn_global_load_lds(
      (const __attribute__((address_space(1))) void*)g,
      (__attribute__((address_space(3))) void*)l, 16, 0, 0);
}

// ---------------- weight transpose + cast: dst[C][R] = (bf16)src[R][C] ----------------
__global__ __launch_bounds__(256) void transpose_wf(const float* __restrict__ src,
                                                    bf16* __restrict__ dst, int R, int C) {
  __shared__ alignas(16) bf16 ts[64 * 65];
  const int tid = threadIdx.x;
  const int r0 = blockIdx.x * 64, c0 = blockIdx.y * 64;
  {
    int rr = tid >> 2, cc = (tid & 3) * 16;
    const float4* p4 = (const float4*)(src + (size_t)(r0 + rr) * C + c0 + cc);
    float fv[16];
#pragma unroll
    for (int q = 0; q < 4; ++q) *(float4*)&fv[q * 4] = p4[q];
#pragma unroll
    for (int i = 0; i < 16; ++i) ts[(cc + i) * 65 + rr] = (bf16)fv[i];
  }
  __syncthreads();
  {
    int rr = tid >> 2, cc = (tid & 3) * 16;
    bf16x8 a, b;
#pragma unroll
    for (int i = 0; i < 8; ++i) a[i] = ts[rr * 65 + cc + i];
#pragma unroll
    for (int i = 0; i < 8; ++i) b[i] = ts[rr * 65 + cc + 8 + i];
    bf16* q = dst + (size_t)(c0 + rr) * R + r0 + cc;
    *(bf16x8*)q = a;
    *(bf16x8*)(q + 8) = b;
  }
}

// ---------------- V transpose: Vt[b][h][f][t] = qkv[b*T+t][2D + h*64 + f] ----------------
__global__ __launch_bounds__(256) void transpose_v(const bf16* __restrict__ qkv,
                                                   bf16* __restrict__ Vt) {
  __shared__ alignas(16) bf16 ts[64 * 65];
  int bid = blockIdx.x;
  const int tt = bid & 31; bid >>= 5;
  const int h = bid & 15;  const int b = bid >> 4;
  const int t0 = tt * 64;
  const int tid = threadIdx.x;
  {
    int tok = tid >> 2, fc = (tid & 3) * 16;
    const bf16* p = qkv + (size_t)(b * T_ + t0 + tok) * (3 * D_) + 2 * D_ + h * DK_ + fc;
    bf16x8 a = *(const bf16x8*)p;
    bf16x8 c = *(const bf16x8*)(p + 8);
#pragma unroll
    for (int i = 0; i < 8; ++i) ts[(fc + i) * 65 + tok] = a[i];
#pragma unroll
    for (int i = 0; i < 8; ++i) ts[(fc + 8 + i) * 65 + tok] = c[i];
  }
  __syncthreads();
  {
    int f = tid >> 2, tc = (tid & 3) * 16;
    bf16x8 a, c;
#pragma unroll
    for (int i = 0; i < 8; ++i) a[i] = ts[f * 65 + tc + i];
#pragma unroll
    for (int i = 0; i < 8; ++i) c[i] = ts[f * 65 + tc + 8 + i];
    bf16* q = Vt + ((size_t)(b * H_ + h) * DK_ + f) * T_ + t0 + tc;
    *(bf16x8*)q = a;
    *(bf16x8*)(q + 8) = c;
  }
}

// ---------------- GEMM: C[M][N] = A[M][K] @ Bt[N][K]^T + bias ----------------
// ASRC=0: A fp32, cast during register staging. ASRC=1: A bf16, DMA-staged.
// B always DMA-staged (m97 pattern). FUSE: Cf32 = C + resid(fp32), stride N.
template <int ASRC, bool FUSE>
__global__ __launch_bounds__(256) void gemm128(const void* __restrict__ Av,
                                               const bf16* __restrict__ Bt,
                                               const float* __restrict__ bias,
                                               bf16* __restrict__ Cbf,
                                               float* __restrict__ Cf,
                                               const float* __restrict__ resid,
                                               int N, int K, int lda, int ldc) {
  __shared__ alignas(16) bf16 As[128 * 32];
  __shared__ alignas(16) bf16 Bs[128 * 32];
  const int tid = threadIdx.x;
  const int wid = tid >> 6, lane = tid & 63, quad = lane >> 4, l16 = lane & 15;
  const int m0 = blockIdx.x * 128, n0 = blockIdx.y * 128;
  const int wr = (wid >> 1) * 64, wc = (wid & 1) * 64;

  f32x4 acc[4][4];
#pragma unroll
  for (int i = 0; i < 4; ++i)
#pragma unroll
    for (int j = 0; j < 4; ++j) acc[i][j] = zero4();

  for (int k0 = 0; k0 < K; k0 += 32) {
    bf16x8 ar[2];
    if (ASRC == 0) {
#pragma unroll
      for (int p = 0; p < 2; ++p) {
        int t = p * 256 + tid;
        int row = t >> 2, kc = (t & 3) * 8;
        const float* ap = (const float*)Av + (size_t)(m0 + row) * lda + k0 + kc;
        float4 a0 = *(const float4*)ap, a1 = *(const float4*)(ap + 4);
        bf16x8 v;
        v[0] = (bf16)a0.x; v[1] = (bf16)a0.y; v[2] = (bf16)a0.z; v[3] = (bf16)a0.w;
        v[4] = (bf16)a1.x; v[5] = (bf16)a1.y; v[6] = (bf16)a1.z; v[7] = (bf16)a1.w;
        ar[p] = v;
      }
    }
    __syncthreads();  // previous iteration's LDS reads complete
#pragma unroll
    for (int p = 0; p < 2; ++p) {
      int t = p * 256 + tid;
      int row = t >> 2, kc = (t & 3) * 8;
      g2l16(Bt + (size_t)(n0 + row) * K + k0 + kc, (char*)Bs + p * 4096 + wid * 1024);
      if (ASRC == 1)
        g2l16((const bf16*)Av + (size_t)(m0 + row) * lda + k0 + kc,
              (char*)As + p * 4096 + wid * 1024);
      else
        *(bf16x8*)&As[row * 32 + kc] = ar[p];
    }
    __syncthreads();
    bf16x8 af[4], bfr[4];
#pragma unroll
    for (int i = 0; i < 4; ++i)
      af[i] = *(const bf16x8*)&As[(wr + i * 16 + l16) * 32 + quad * 8];
#pragma unroll
    for (int j = 0; j < 4; ++j)
      bfr[j] = *(const bf16x8*)&Bs[(wc + j * 16 + l16) * 32 + quad * 8];
#pragma unroll
    for (int i = 0; i < 4; ++i)
#pragma unroll
      for (int j = 0; j < 4; ++j)
        acc[i][j] = __builtin_amdgcn_mfma_f32_16x16x32_bf16(af[i], bfr[j], acc[i][j], 0, 0, 0);
  }

#pragma unroll
  for (int i = 0; i < 4; ++i) {
#pragma unroll
    for (int j = 0; j < 4; ++j) {
      const int col = n0 + wc + j * 16 + l16;
      const float bv = bias[col];
#pragma unroll
      for (int r = 0; r < 4; ++r) {
        const int row = m0 + wr + i * 16 + quad * 4 + r;
        const float v = acc[i][j][r] + bv;
        if (FUSE) {
          const size_t off = (size_t)row * N + col;
          Cf[off] = v + resid[off];
        } else {
          Cbf[(size_t)row * ldc + col] = (bf16)v;
        }
      }
    }
  }
}

// ---------------- flash attention: block = (b, h, 128 q-rows), 8 waves x 16 rows ----------------
// S^T = K Q^T (C-layout row=key, col=qrow); P stays in registers feeding 16x16x16 PV.
// Softmax in log2 domain. Register-prefetch software pipeline: tile kt+1's K/V global loads
// issue at the start of tile kt's compute, so the barrier no longer serializes load latency.
__global__ __launch_bounds__(512) void attn128(const bf16* __restrict__ qkv,
                                               const bf16* __restrict__ Vt,
                                               bf16* __restrict__ out) {
  __shared__ alignas(16) bf16 Ks[128 * 72];      // [key][f], stride 72
  __shared__ alignas(16) bf16 Vs[64 * 136];      // [f][key], stride 136
  const int tid = threadIdx.x;
  const int wid = tid >> 6, lane = tid & 63, quad = lane >> 4, l16 = lane & 15;
  const int bid = blockIdx.x;
  const int qb = bid & 15, h = (bid >> 4) & 15, b = bid >> 8;
  const int q0 = qb * 128;

  // staging addresses (thread-invariant across tiles except kt*128)
  const int skey = tid >> 3, sf = (tid & 7) * 8;          // K: tid covers 64 keys x 8 f-chunks
  const int svf = tid >> 4, skc = (tid & 15) * 8;         // V: 32 f-rows x 16 key-chunks
  const bf16* kbase = qkv + (size_t)(b * T_ + skey) * (3 * D_) + D_ + h * DK_ + sf;
  const bf16* vbase = Vt + ((size_t)(b * H_ + h) * DK_ + svf) * T_ + skc;

  // Q as MFMA B-operand (k=quad*8+j, n=qrow=l16), pre-scaled by log2e/8
  const float SC = 0.125f * 1.44269504f;
  bf16x8 qf[2];
  {
    const bf16* qp = qkv + (size_t)(b * T_ + q0 + wid * 16 + l16) * (3 * D_) + h * DK_ + quad * 8;
    qf[0] = *(const bf16x8*)qp;
    qf[1] = *(const bf16x8*)(qp + 32);
#pragma unroll
    for (int i = 0; i < 8; ++i) { qf[0][i] = (bf16)((float)qf[0][i] * SC);
                                  qf[1][i] = (bf16)((float)qf[1][i] * SC); }
  }

  float mi = -1e30f, li = 0.f;   // per-lane: qrow = l16 (replicated across quads)
  f32x4 o[4];                    // o[ft][r] = O[qrow=quad*4+r][f=ft*16+l16]
#pragma unroll
  for (int ft = 0; ft < 4; ++ft) o[ft] = zero4();

  // prefetch tile 0 into registers
  bf16x8 kr[2], vr[2];
#pragma unroll
  for (int p = 0; p < 2; ++p) {
    kr[p] = *(const bf16x8*)(kbase + (size_t)(p * 64) * (3 * D_));
    vr[p] = *(const bf16x8*)(vbase + (size_t)(p * 32) * T_);
  }

  for (int kt = 0; kt < T_ / 128; ++kt) {
    __syncthreads();               // prior tile's LDS reads complete
#pragma unroll
    for (int p = 0; p < 2; ++p) {
      *(bf16x8*)&Ks[(skey + p * 64) * 72 + sf] = kr[p];
      *(bf16x8*)&Vs[(svf + p * 32) * 136 + skc] = vr[p];
    }
    __syncthreads();
    if (kt + 1 < T_ / 128) {       // issue next tile's loads; consumed next iteration
      const size_t koff = (size_t)(kt + 1) * 128;
#pragma unroll
      for (int p = 0; p < 2; ++p) {
        kr[p] = *(const bf16x8*)(kbase + (koff + p * 64) * (3 * D_));
        vr[p] = *(const bf16x8*)(vbase + (size_t)(p * 32) * T_ + koff);
      }
    }

    // S^T tile (log2 domain): sv[nt] reg r = S2[key = nt*16+quad*4+r][qrow = l16]
    f32x4 sv[8];
#pragma unroll
    for (int nt = 0; nt < 8; ++nt) sv[nt] = zero4();
#pragma unroll
    for (int nt = 0; nt < 8; ++nt)
#pragma unroll
      for (int ks = 0; ks < 2; ++ks) {
        bf16x8 kf = *(const bf16x8*)&Ks[(nt * 16 + l16) * 72 + ks * 32 + quad * 8];
        sv[nt] = __builtin_amdgcn_mfma_f32_16x16x32_bf16(kf, qf[ks], sv[nt], 0, 0, 0);
      }

    // online softmax (base-2): lane owns 32 scores of qrow=l16
    float tmax = mi;
#pragma unroll
    for (int nt = 0; nt < 8; ++nt)
#pragma unroll
      for (int r = 0; r < 4; ++r) tmax = fmaxf(tmax, sv[nt][r]);
    tmax = fmaxf(tmax, __shfl_xor(tmax, 16, 64));
    tmax = fmaxf(tmax, __shfl_xor(tmax, 32, 64));
    const float alpha = exp2f(mi - tmax);
    mi = tmax;
    float s = 0.f;
#pragma unroll
    for (int nt = 0; nt < 8; ++nt)
#pragma unroll
      for (int r = 0; r < 4; ++r) {
        float pe = exp2f(sv[nt][r] - tmax);
        sv[nt][r] = pe; s += pe;
      }
    s += __shfl_xor(s, 16, 64);
    s += __shfl_xor(s, 32, 64);
    li = li * alpha + s;

    // rescale O: row quad*4+r's alpha lives at lane quad*4+r
#pragma unroll
    for (int r = 0; r < 4; ++r) {
      const float ar = __shfl(alpha, quad * 4 + r, 64);
#pragma unroll
      for (int ft = 0; ft < 4; ++ft) o[ft][r] *= ar;
    }

    // O += P V via 16x16x16 (A=P in registers: k=key=ks*16+quad*4+j)
#pragma unroll
    for (int ks = 0; ks < 8; ++ks) {
      union { bf16x4 b; s16x4 s; } pf;
#pragma unroll
      for (int j = 0; j < 4; ++j) pf.b[j] = (bf16)sv[ks][j];
#pragma unroll
      for (int ft = 0; ft < 4; ++ft) {
        const s16x4 vf = *(const s16x4*)&Vs[(ft * 16 + l16) * 136 + ks * 16 + quad * 4];
        o[ft] = __builtin_amdgcn_mfma_f32_16x16x16bf16_1k(pf.s, vf, o[ft], 0, 0, 0);
      }
    }
  }

  // epilogue: normalize rows (li for qrow=quad*4+r lives at lane quad*4+r)
#pragma unroll
  for (int r = 0; r < 4; ++r) {
    const float inv = 1.0f / __shfl(li, quad * 4 + r, 64);
    const int row = b * T_ + q0 + wid * 16 + quad * 4 + r;
#pragma unroll
    for (int ft = 0; ft < 4; ++ft)
      out[(size_t)row * (3 * D_) + h * DK_ + ft * 16 + l16] = (bf16)(o[ft][r] * inv);
  }
}

// ---------------- layernorm: one wave per row, in-place, no LDS/barrier ----------------
__global__ __launch_bounds__(256) void ln_out(float* __restrict__ res,
                                              const float* __restrict__ gamma,
                                              const float* __restrict__ beta) {
  const int row = blockIdx.x * 4 + (threadIdx.x >> 6);
  const int lane = threadIdx.x & 63;
  float4 v[4];
  float s = 0.f, q = 0.f;
#pragma unroll
  for (int p = 0; p < 4; ++p) {
    v[p] = *(const float4*)(res + (size_t)row * D_ + p * 256 + lane * 4);
    s += v[p].x + v[p].y + v[p].z + v[p].w;
    q += v[p].x * v[p].x + v[p].y * v[p].y + v[p].z * v[p].z + v[p].w * v[p].w;
  }
#pragma unroll
  for (int m = 1; m < 64; m <<= 1) { s += __shfl_xor(s, m, 64); q += __shfl_xor(q, m, 64); }
  const float mu = s * (1.0f / D_);
  const float var = q * (1.0f / D_) - mu * mu;
  const float rstd = rsqrtf(var + 1e-5f);
#pragma unroll
  for (int p = 0; p < 4; ++p) {
    const int c = p * 256 + lane * 4;
    const float4 g = *(const float4*)(gamma + c);
    const float4 be = *(const float4*)(beta + c);
    float4 ov;
    ov.x = (v[p].x - mu) * rstd * g.x + be.x;
    ov.y = (v[p].y - mu) * rstd * g.y + be.y;
    ov.z = (v[p].z - mu) * rstd * g.z + be.z;
    ov.w = (v[p].w - mu) * rstd * g.w + be.w;
    *(float4*)(res + (size_t)row * D_ + c) = ov;
  }
}

extern "C" void kernel_launch(void* const* d_in, const int* in_sizes, int n_in,
                              void* d_out, int out_size, void* d_ws, size_t ws_size,
                              hipStream_t stream) {
  const float* x     = (const float*)d_in[0];
  const float* Wqkv  = (const float*)d_in[1];
  const float* bqkv  = (const float*)d_in[2];
  const float* Wout  = (const float*)d_in[3];
  const float* bout  = (const float*)d_in[4];
  const float* gamma = (const float*)d_in[5];
  const float* beta  = (const float*)d_in[6];
  float* out = (float*)d_out;  // fp32 residual buffer too (LN in-place)

  // workspace layout (75.5 MB, proven footprint):
  char* ws = (char*)d_ws;
  bf16* WqkvT = (bf16*)ws; ws += (size_t)3 * D_ * D_ * 2;        // [3072][1024]
  bf16* WoutT = (bf16*)ws; ws += (size_t)D_ * D_ * 2;            // [1024][1024]
  bf16* qkv   = (bf16*)ws; ws += (size_t)M_ * 3 * D_ * 2;        // [8192][3072]
  bf16* Vt    = (bf16*)ws;                                       // [4][16][64][2048]
  bf16* attn  = qkv + 2 * D_;  // attn output overwrites qkv's V columns (dead after transpose_v)

  transpose_wf<<<dim3(D_ / 64, 3 * D_ / 64), 256, 0, stream>>>(Wqkv, WqkvT, D_, 3 * D_);
  transpose_wf<<<dim3(D_ / 64, D_ / 64), 256, 0, stream>>>(Wout, WoutT, D_, D_);
  gemm128<0, false><<<dim3(M_ / 128, 3 * D_ / 128), 256, 0, stream>>>(
      x, WqkvT, bqkv, qkv, nullptr, nullptr, 3 * D_, D_, D_, 3 * D_);
  transpose_v<<<B_ * H_ * (T_ / 64), 256, 0, stream>>>(qkv, Vt);
  attn128<<<B_ * H_ * (T_ / 128), 512, 0, stream>>>(qkv, Vt, attn);
  gemm128<1, true><<<dim3(M_ / 128, D_ / 128), 256, 0, stream>>>(
      attn, WoutT, bout, nullptr, out, x, D_, D_, 3 * D_, D_);
  ln_out<<<M_ / 4, 256, 0, stream>>>(out, gamma, beta);
}